// Round 3
// baseline (6757.710 us; speedup 1.0000x reference)
//
#include <hip/hip_runtime.h>
#include <stdint.h>

// LSTMModel: 4-layer LSTM (B=256,T=512,H=256,Din=28) + sigmoid proj (21)
// R3: batch all A-fragment MALL loads into registers (1 round trip/step),
// per-producer flag slots polled with parallel u64 loads, 4-deep h ring,
// 16-slot LDS XOR swizzle.

#define B 256
#define T 512
#define H 256
#define DIN 28
#define NWG 256
#define OUTD 21

typedef __attribute__((ext_vector_type(8))) __bf16 bf16x8;
typedef __attribute__((ext_vector_type(4))) float f32x4;
typedef __attribute__((ext_vector_type(4))) unsigned short u16x4;
typedef unsigned long long u64;

// ---- workspace layout (bytes) ----
#define WS_SLOTS 0ull                                   // 32 grp * 16 u32 = 2 KB
#define WS_HBUF  2048ull                                // [l][slot4][b][j] bf16: 2 MiB
#define WS_H3F   (WS_HBUF + 4ull*4*B*H*2)               // layer-3 last h, f32: 256 KiB
#define WS_XBF   (WS_H3F + (u64)B*H*4)                  // x bf16 [b][t][32]: 8 MiB
#define WS_WIH0  (WS_XBF + (u64)B*T*32*2)
#define WS_WIHR  (WS_WIH0 + 1024ull*32*2)
#define WS_WHHR  (WS_WIHR + 3ull*1024*256*2)
#define WS_BIAS  (WS_WHHR + 4ull*1024*256*2)
#define WS_ZERO  WS_XBF                                 // zero slots+hbuf+h3f

__device__ __forceinline__ unsigned short f2bf(float f) {
  unsigned u = __builtin_bit_cast(unsigned, f);
  u += 0x7fffu + ((u >> 16) & 1u);
  return (unsigned short)(u >> 16);
}
__device__ __forceinline__ float sigf(float x) { return 1.f / (1.f + __expf(-x)); }
__device__ __forceinline__ float tanhfast(float x) {
  float e = __expf(2.f * x);
  return 1.f - 2.f / (e + 1.f);
}
__device__ __forceinline__ bf16x8 ldb8(const void* p) { return *(const bf16x8*)p; }

__device__ __forceinline__ bf16x8 ldg_coh16(const unsigned short* p) {
  union { u64 q[2]; bf16x8 v; } u;
  u.q[0] = __hip_atomic_load((const u64*)p, __ATOMIC_RELAXED, __HIP_MEMORY_SCOPE_AGENT);
  u.q[1] = __hip_atomic_load((const u64*)p + 1, __ATOMIC_RELAXED, __HIP_MEMORY_SCOPE_AGENT);
  return u.v;
}
__device__ __forceinline__ void stg_coh8(void* p, u64 v) {
  __hip_atomic_store((u64*)p, v, __ATOMIC_RELAXED, __HIP_MEMORY_SCOPE_AGENT);
}
__device__ __forceinline__ u64 ldq(const u64* p) {
  return __hip_atomic_load(p, __ATOMIC_RELAXED, __HIP_MEMORY_SCOPE_AGENT);
}
__device__ __forceinline__ bool chk2(u64 v, unsigned tgt) {
  return ((unsigned)v >= tgt) && ((unsigned)(v >> 32) >= tgt);
}

// ---------------- prep kernels ----------------
__global__ void prep_x(const float* __restrict__ x, unsigned short* __restrict__ xbf) {
  int tot = B * T * 32;
  for (int idx = blockIdx.x * blockDim.x + threadIdx.x; idx < tot;
       idx += gridDim.x * blockDim.x) {
    int kk = idx & 31;
    int bt = idx >> 5;
    float v = (kk < DIN) ? x[(size_t)bt * DIN + kk] : 0.f;
    xbf[idx] = f2bf(v);
  }
}

__global__ void prep_w(const float* __restrict__ wih0, const float* __restrict__ wihrest,
                       const float* __restrict__ whh, const float* __restrict__ bih,
                       const float* __restrict__ bhh,
                       unsigned short* __restrict__ wih0r, unsigned short* __restrict__ wihr,
                       unsigned short* __restrict__ whhr, float* __restrict__ biasr) {
  const int R0 = 1024 * 32, R1 = 3 * 1024 * 256, R2 = 4 * 1024 * 256, R3 = 4 * 1024;
  int tot = R0 + R1 + R2 + R3;
  for (int idx = blockIdx.x * blockDim.x + threadIdx.x; idx < tot;
       idx += gridDim.x * blockDim.x) {
    if (idx < R0) {
      int k = idx & 31, np = idx >> 5, g = np & 3, j = np >> 2;
      wih0r[idx] = f2bf(k < DIN ? wih0[(size_t)(g * 256 + j) * DIN + k] : 0.f);
    } else if (idx < R0 + R1) {
      int i = idx - R0;
      int k = i & 255, r = i >> 8, np = r & 1023, l = r >> 10, g = np & 3, j = np >> 2;
      wihr[i] = f2bf(wihrest[((size_t)l * 1024 + g * 256 + j) * 256 + k]);
    } else if (idx < R0 + R1 + R2) {
      int i = idx - R0 - R1;
      int k = i & 255, r = i >> 8, np = r & 1023, l = r >> 10, g = np & 3, j = np >> 2;
      whhr[i] = f2bf(whh[((size_t)l * 1024 + g * 256 + j) * 256 + k]);
    } else {
      int i = idx - R0 - R1 - R2;
      int np = i & 1023, l = i >> 10, g = np & 3, j = np >> 2;
      biasr[i] = bih[l * 1024 + g * 256 + j] + bhh[l * 1024 + g * 256 + j];
    }
  }
}

// ---------------- main persistent kernel ----------------
__device__ __forceinline__ void mstep(bf16x8 a0, bf16x8 a1, const unsigned char* Ws,
                                      int wkcol, int akoff, int brow0, int brow1,
                                      f32x4& a00, f32x4& a01, f32x4& a10, f32x4& a11) {
  int kb = (wkcol + akoff) * 2;
  bf16x8 b0 = ldb8(Ws + brow0 * 1024 + (kb ^ ((brow0 & 15) << 4)));
  bf16x8 b1 = ldb8(Ws + brow1 * 1024 + (kb ^ ((brow1 & 15) << 4)));
  a00 = __builtin_amdgcn_mfma_f32_16x16x32_bf16(a0, b0, a00, 0, 0, 0);
  a01 = __builtin_amdgcn_mfma_f32_16x16x32_bf16(a0, b1, a01, 0, 0, 0);
  a10 = __builtin_amdgcn_mfma_f32_16x16x32_bf16(a1, b0, a10, 0, 0, 0);
  a11 = __builtin_amdgcn_mfma_f32_16x16x32_bf16(a1, b1, a11, 0, 0, 0);
}

__launch_bounds__(256, 1)
__global__ void lstm_main(const unsigned short* __restrict__ xbf,
                          const unsigned short* __restrict__ wih0r,
                          const unsigned short* __restrict__ wihr,
                          const unsigned short* __restrict__ whhr,
                          const float* __restrict__ biasr,
                          const float* __restrict__ Wout, const float* __restrict__ bout,
                          unsigned short* __restrict__ hbuf, float* __restrict__ h3f,
                          unsigned* __restrict__ slots, float* __restrict__ out) {
  __shared__ unsigned char Ws[64 * 1024];   // 64 weight rows x 1KB, XOR-swizzled
  __shared__ float gates[64 * 68];          // [n'rel][brel] exchange, stride 68

  const int tid = threadIdx.x;
  const int lane = tid & 63;
  const int w = tid >> 6;
  const int wb = w >> 1, wn = w & 1;
  const int bid = blockIdx.x;
  const int layer = (bid & 7) >> 1;
  const int wgl = ((bid >> 3) << 1) | (bid & 1);
  const int b0g = wgl >> 4;
  const int b0 = b0g * 64;
  const int ntile = wgl & 15;
  const int n0 = ntile * 64;
  const int j0 = ntile * 16;
  const int mygrp = layer * 4 + b0g;

  // ---- load resident weight slice into LDS (once) ----
  const int ngr = (layer == 0) ? 36 : 64;
  for (int i = tid; i < 64 * ngr; i += 256) {
    int row = i / ngr, blk = i % ngr;
    uint4 v;
    if (layer == 0) {
      if (blk < 4) v = *(const uint4*)(wih0r + (size_t)(n0 + row) * 32 + blk * 8);
      else v = *(const uint4*)(whhr + (size_t)(n0 + row) * 256 + (blk - 4) * 8);
    } else {
      if (blk < 32)
        v = *(const uint4*)(wihr + ((size_t)(layer - 1) * 1024 + n0 + row) * 256 + blk * 8);
      else
        v = *(const uint4*)(whhr + ((size_t)layer * 1024 + n0 + row) * 256 + (blk - 32) * 8);
    }
    *(uint4*)(Ws + row * 1024 + ((blk * 16) ^ ((row & 15) << 4))) = v;
  }
  const float bv0 = biasr[layer * 1024 + n0 + wn * 32 + (lane & 15)];
  const float bv1 = biasr[layer * 1024 + n0 + wn * 32 + 16 + (lane & 15)];
  __syncthreads();

  const int arow0 = b0 + wb * 32 + (lane & 15);
  const int arow1 = arow0 + 16;
  const int akoff = (lane >> 4) * 8;
  const int brow0 = wn * 32 + (lane & 15);
  const int brow1 = brow0 + 16;

  // poll bases (u64 index); absent edges -> own group with target 0 (always true)
  const u64* sq = (const u64*)slots;
  const int grec = mygrp * 8;
  const int gprev = (layer > 0) ? (mygrp - 4) * 8 : grec;
  const int gdown = (layer < 3) ? (mygrp + 4) * 8 : grec;

  f32x4 creg = {0.f, 0.f, 0.f, 0.f};

  for (int t = 0; t < T; ++t) {
    const int sw = t & 3;              // write slot
    const int sr = (t + 3) & 3;        // rec read slot (t-1)
    unsigned short* hbW = hbuf + ((size_t)layer * 4 + sw) * 65536;
    const unsigned short* hbR = hbuf + ((size_t)layer * 4 + sr) * 65536;

    // layer-0 x fragments: independent of flags, issue early
    bf16x8 ax0, ax1;
    if (layer == 0) {
      ax0 = ldb8(xbf + ((size_t)arow0 * T + t) * 32 + akoff);
      ax1 = ldb8(xbf + ((size_t)arow1 * T + t) * 32 + akoff);
    }

    // ---- dataflow wait: all three edges polled in one round trip ----
    {
      const unsigned trec = (unsigned)t;
      const unsigned tprev = (layer > 0) ? (unsigned)(t + 1) : 0u;
      const unsigned tdown = (layer < 3 && t >= 4) ? (unsigned)(t - 3) : 0u;
      for (;;) {
        u64 v[24];
#pragma unroll
        for (int i = 0; i < 8; ++i) v[i] = ldq(sq + grec + i);
#pragma unroll
        for (int i = 0; i < 8; ++i) v[8 + i] = ldq(sq + gprev + i);
#pragma unroll
        for (int i = 0; i < 8; ++i) v[16 + i] = ldq(sq + gdown + i);
        bool ok = true;
#pragma unroll
        for (int i = 0; i < 8; ++i) ok = ok && chk2(v[i], trec);
#pragma unroll
        for (int i = 0; i < 8; ++i) ok = ok && chk2(v[8 + i], tprev);
#pragma unroll
        for (int i = 0; i < 8; ++i) ok = ok && chk2(v[16 + i], tdown);
        if (ok) break;
        __builtin_amdgcn_s_sleep(1);
      }
      asm volatile("" ::: "memory");
    }

    f32x4 a00 = {bv0, bv0, bv0, bv0};
    f32x4 a01 = {bv1, bv1, bv1, bv1};
    f32x4 a10 = a00, a11 = a01;

    if (layer == 0) {
      // batch rec loads (8 ksteps x 2 rows)
      bf16x8 aR[16];
#pragma unroll
      for (int ki = 0; ki < 8; ++ki) {
        aR[2 * ki] = ldg_coh16(hbR + (size_t)arow0 * 256 + ki * 32 + akoff);
        aR[2 * ki + 1] = ldg_coh16(hbR + (size_t)arow1 * 256 + ki * 32 + akoff);
      }
      mstep(ax0, ax1, Ws, 0, akoff, brow0, brow1, a00, a01, a10, a11);
#pragma unroll
      for (int ki = 0; ki < 8; ++ki)
        mstep(aR[2 * ki], aR[2 * ki + 1], Ws, (ki + 1) * 32, akoff, brow0, brow1,
              a00, a01, a10, a11);
    } else {
      const unsigned short* hbP = hbuf + ((size_t)(layer - 1) * 4 + sw) * 65536;
      bf16x8 aP[16], aR[16];
#pragma unroll
      for (int ki = 0; ki < 8; ++ki) {
        aP[2 * ki] = ldg_coh16(hbP + (size_t)arow0 * 256 + ki * 32 + akoff);
        aP[2 * ki + 1] = ldg_coh16(hbP + (size_t)arow1 * 256 + ki * 32 + akoff);
      }
#pragma unroll
      for (int ki = 0; ki < 8; ++ki) {
        aR[2 * ki] = ldg_coh16(hbR + (size_t)arow0 * 256 + ki * 32 + akoff);
        aR[2 * ki + 1] = ldg_coh16(hbR + (size_t)arow1 * 256 + ki * 32 + akoff);
      }
#pragma unroll
      for (int ki = 0; ki < 8; ++ki)
        mstep(aP[2 * ki], aP[2 * ki + 1], Ws, ki * 32, akoff, brow0, brow1,
              a00, a01, a10, a11);
#pragma unroll
      for (int ki = 0; ki < 8; ++ki)
        mstep(aR[2 * ki], aR[2 * ki + 1], Ws, (ki + 8) * 32, akoff, brow0, brow1,
              a00, a01, a10, a11);
    }

    // scatter acc frags to LDS: gates[n'rel][brel]
    {
      int c = lane & 15, Rg = lane >> 4;
      *(f32x4*)&gates[(wn * 32 + c) * 68 + wb * 32 + Rg * 4] = a00;
      *(f32x4*)&gates[(wn * 32 + 16 + c) * 68 + wb * 32 + Rg * 4] = a01;
      *(f32x4*)&gates[(wn * 32 + c) * 68 + wb * 32 + 16 + Rg * 4] = a10;
      *(f32x4*)&gates[(wn * 32 + 16 + c) * 68 + wb * 32 + 16 + Rg * 4] = a11;
    }
    __syncthreads();
    // activations + cell update (c in regs) + coherent h store
    {
      int brel = tid & 63, jq = tid >> 6;
      int b = b0 + brel;
      int jb = j0 + jq * 4;
      f32x4 cnew;
      float hv[4];
#pragma unroll
      for (int i2 = 0; i2 < 4; ++i2) {
        int jr = jq * 4 + i2;
        float ip = gates[(4 * jr + 0) * 68 + brel];
        float fp = gates[(4 * jr + 1) * 68 + brel];
        float gp = gates[(4 * jr + 2) * 68 + brel];
        float op = gates[(4 * jr + 3) * 68 + brel];
        float ii = sigf(ip), ff = sigf(fp), gg = tanhfast(gp), oo = sigf(op);
        float cc = ff * creg[i2] + ii * gg;
        cnew[i2] = cc;
        hv[i2] = oo * tanhfast(cc);
      }
      creg = cnew;
      u16x4 h4 = {f2bf(hv[0]), f2bf(hv[1]), f2bf(hv[2]), f2bf(hv[3])};
      stg_coh8(hbW + (size_t)b * H + jb, __builtin_bit_cast(u64, h4));
      if (layer == 3 && t == T - 1) {
        float2 p01 = make_float2(hv[0], hv[1]);
        float2 p23 = make_float2(hv[2], hv[3]);
        stg_coh8(h3f + (size_t)b * H + jb, __builtin_bit_cast(u64, p01));
        stg_coh8(h3f + (size_t)b * H + jb + 2, __builtin_bit_cast(u64, p23));
      }
    }
    // drain write-through stores, then publish own slot (plain relaxed store)
    asm volatile("s_waitcnt vmcnt(0)" ::: "memory");
    __syncthreads();
    if (tid == 0)
      __hip_atomic_store(&slots[mygrp * 16 + ntile], (unsigned)(t + 1),
                         __ATOMIC_RELAXED, __HIP_MEMORY_SCOPE_AGENT);
  }

  // ---- final projection by layer-3 WGs: 4 b each ----
  if (layer == 3) {
    for (;;) {
      u64 v[8];
      bool ok = true;
#pragma unroll
      for (int i = 0; i < 8; ++i) v[i] = ldq(sq + grec + i);
#pragma unroll
      for (int i = 0; i < 8; ++i) ok = ok && chk2(v[i], (unsigned)T);
      if (ok) break;
      __builtin_amdgcn_s_sleep(1);
    }
    asm volatile("" ::: "memory");
    for (int i = tid; i < 4 * 128; i += 256) {
      int bi = i >> 7, jj = (i & 127) * 2;
      u64 q = ldq((const u64*)(h3f + (size_t)(b0 + ntile * 4 + bi) * H + jj));
      float2 hf = __builtin_bit_cast(float2, q);
      gates[bi * 260 + jj] = hf.x;
      gates[bi * 260 + jj + 1] = hf.y;
    }
    __syncthreads();
    if (tid < 4 * OUTD) {
      int o = tid % OUTD, bi = tid / OUTD;
      int b = b0 + ntile * 4 + bi;
      const float* wr = Wout + (size_t)o * H;
      const float* hr = &gates[bi * 260];
      float sum = bout[o];
#pragma unroll 8
      for (int j = 0; j < H; ++j) sum = fmaf(hr[j], wr[j], sum);
      out[b * OUTD + o] = sigf(sum);
    }
  }
}

extern "C" void kernel_launch(void* const* d_in, const int* in_sizes, int n_in,
                              void* d_out, int out_size, void* d_ws, size_t ws_size,
                              hipStream_t stream) {
  const float* x = (const float*)d_in[0];
  const float* Wih0 = (const float*)d_in[1];
  const float* WihRest = (const float*)d_in[2];
  const float* Whh = (const float*)d_in[3];
  const float* bih = (const float*)d_in[4];
  const float* bhh = (const float*)d_in[5];
  const float* Wout = (const float*)d_in[6];
  const float* bout = (const float*)d_in[7];
  float* out = (float*)d_out;
  char* ws = (char*)d_ws;

  unsigned* slots = (unsigned*)(ws + WS_SLOTS);
  unsigned short* hbuf = (unsigned short*)(ws + WS_HBUF);
  float* h3f = (float*)(ws + WS_H3F);
  unsigned short* xbf = (unsigned short*)(ws + WS_XBF);
  unsigned short* wih0r = (unsigned short*)(ws + WS_WIH0);
  unsigned short* wihr = (unsigned short*)(ws + WS_WIHR);
  unsigned short* whhr = (unsigned short*)(ws + WS_WHHR);
  float* biasr = (float*)(ws + WS_BIAS);

  hipMemsetAsync(ws, 0, (size_t)WS_ZERO, stream);
  prep_x<<<2048, 256, 0, stream>>>(x, xbf);
  prep_w<<<2048, 256, 0, stream>>>(Wih0, WihRest, Whh, bih, bhh, wih0r, wihr, whhr, biasr);
  lstm_main<<<NWG, 256, 0, stream>>>(xbf, wih0r, wihr, whhr, biasr, Wout, bout, hbuf,
                                     h3f, slots, out);
}

// Round 4
// 2760.122 us; speedup vs baseline: 2.4483x; 2.4483x over previous
//
#include <hip/hip_runtime.h>
#include <stdint.h>

// LSTMModel: 4-layer LSTM (B=256,T=512,H=256,Din=28) + sigmoid proj (21)
// R4: single-thread poll on aggregated counters (atomicAdd publish),
// WG-cooperative LDS staging of the A-panel with sched_barrier(0)-forced
// in-flight coherent loads. A and B frags both read from swizzled LDS.

#define B 256
#define T 512
#define H 256
#define DIN 28
#define NWG 256
#define OUTD 21

typedef __attribute__((ext_vector_type(8))) __bf16 bf16x8;
typedef __attribute__((ext_vector_type(4))) float f32x4;
typedef __attribute__((ext_vector_type(4))) unsigned short u16x4;
typedef unsigned long long u64;

// ---- workspace layout (bytes) ----
#define WS_FLAGS 0ull                                   // 32 grp * 512 t * u32 = 64 KB
#define WS_HBUF  65536ull                               // [l][slot4][b][j] bf16: 2 MiB
#define WS_H3F   (WS_HBUF + 4ull*4*B*H*2)               // layer-3 last h, f32: 256 KiB
#define WS_XBF   (WS_H3F + (u64)B*H*4)                  // x bf16 [b][t][32]: 8 MiB
#define WS_WIH0  (WS_XBF + (u64)B*T*32*2)
#define WS_WIHR  (WS_WIH0 + 1024ull*32*2)
#define WS_WHHR  (WS_WIHR + 3ull*1024*256*2)
#define WS_BIAS  (WS_WHHR + 4ull*1024*256*2)
#define WS_ZERO  WS_XBF                                 // zero flags+hbuf+h3f

__device__ __forceinline__ unsigned short f2bf(float f) {
  unsigned u = __builtin_bit_cast(unsigned, f);
  u += 0x7fffu + ((u >> 16) & 1u);
  return (unsigned short)(u >> 16);
}
__device__ __forceinline__ float sigf(float x) { return 1.f / (1.f + __expf(-x)); }
__device__ __forceinline__ float tanhfast(float x) {
  float e = __expf(2.f * x);
  return 1.f - 2.f / (e + 1.f);
}
__device__ __forceinline__ bf16x8 ldb8(const void* p) { return *(const bf16x8*)p; }

__device__ __forceinline__ void stg_coh8(void* p, u64 v) {
  __hip_atomic_store((u64*)p, v, __ATOMIC_RELAXED, __HIP_MEMORY_SCOPE_AGENT);
}
__device__ __forceinline__ u64 ldq(const u64* p) {
  return __hip_atomic_load(p, __ATOMIC_RELAXED, __HIP_MEMORY_SCOPE_AGENT);
}
__device__ __forceinline__ unsigned ldflag(const unsigned* f) {
  return __hip_atomic_load(f, __ATOMIC_RELAXED, __HIP_MEMORY_SCOPE_AGENT);
}

// ---------------- prep kernels ----------------
__global__ void prep_x(const float* __restrict__ x, unsigned short* __restrict__ xbf) {
  int tot = B * T * 32;
  for (int idx = blockIdx.x * blockDim.x + threadIdx.x; idx < tot;
       idx += gridDim.x * blockDim.x) {
    int kk = idx & 31;
    int bt = idx >> 5;
    float v = (kk < DIN) ? x[(size_t)bt * DIN + kk] : 0.f;
    xbf[idx] = f2bf(v);
  }
}

__global__ void prep_w(const float* __restrict__ wih0, const float* __restrict__ wihrest,
                       const float* __restrict__ whh, const float* __restrict__ bih,
                       const float* __restrict__ bhh,
                       unsigned short* __restrict__ wih0r, unsigned short* __restrict__ wihr,
                       unsigned short* __restrict__ whhr, float* __restrict__ biasr) {
  const int R0 = 1024 * 32, R1 = 3 * 1024 * 256, R2 = 4 * 1024 * 256, R3 = 4 * 1024;
  int tot = R0 + R1 + R2 + R3;
  for (int idx = blockIdx.x * blockDim.x + threadIdx.x; idx < tot;
       idx += gridDim.x * blockDim.x) {
    if (idx < R0) {
      int k = idx & 31, np = idx >> 5, g = np & 3, j = np >> 2;
      wih0r[idx] = f2bf(k < DIN ? wih0[(size_t)(g * 256 + j) * DIN + k] : 0.f);
    } else if (idx < R0 + R1) {
      int i = idx - R0;
      int k = i & 255, r = i >> 8, np = r & 1023, l = r >> 10, g = np & 3, j = np >> 2;
      wihr[i] = f2bf(wihrest[((size_t)l * 1024 + g * 256 + j) * 256 + k]);
    } else if (idx < R0 + R1 + R2) {
      int i = idx - R0 - R1;
      int k = i & 255, r = i >> 8, np = r & 1023, l = r >> 10, g = np & 3, j = np >> 2;
      whhr[i] = f2bf(whh[((size_t)l * 1024 + g * 256 + j) * 256 + k]);
    } else {
      int i = idx - R0 - R1 - R2;
      int np = i & 1023, l = i >> 10, g = np & 3, j = np >> 2;
      biasr[i] = bih[l * 1024 + g * 256 + j] + bhh[l * 1024 + g * 256 + j];
    }
  }
}

// ---------------- main persistent kernel ----------------
__device__ __forceinline__ bf16x8 lds_frag(const unsigned char* base, int row, int kb) {
  return *(const bf16x8*)(base + row * 1024 + (kb ^ ((row & 15) << 4)));
}

__device__ __forceinline__ void mstep(const unsigned char* Ast, const unsigned char* Ws,
                                      int kb, int ar0, int ar1, int br0, int br1,
                                      f32x4& a00, f32x4& a01, f32x4& a10, f32x4& a11) {
  bf16x8 a0 = lds_frag(Ast, ar0, kb);
  bf16x8 a1 = lds_frag(Ast, ar1, kb);
  bf16x8 b0 = lds_frag(Ws, br0, kb);
  bf16x8 b1 = lds_frag(Ws, br1, kb);
  a00 = __builtin_amdgcn_mfma_f32_16x16x32_bf16(a0, b0, a00, 0, 0, 0);
  a01 = __builtin_amdgcn_mfma_f32_16x16x32_bf16(a0, b1, a01, 0, 0, 0);
  a10 = __builtin_amdgcn_mfma_f32_16x16x32_bf16(a1, b0, a10, 0, 0, 0);
  a11 = __builtin_amdgcn_mfma_f32_16x16x32_bf16(a1, b1, a11, 0, 0, 0);
}

__launch_bounds__(256, 1)
__global__ void lstm_main(const unsigned short* __restrict__ xbf,
                          const unsigned short* __restrict__ wih0r,
                          const unsigned short* __restrict__ wihr,
                          const unsigned short* __restrict__ whhr,
                          const float* __restrict__ biasr,
                          const float* __restrict__ Wout, const float* __restrict__ bout,
                          unsigned short* __restrict__ hbuf, float* __restrict__ h3f,
                          unsigned* __restrict__ flags, float* __restrict__ out) {
  __shared__ unsigned char Ws[64 * 1024];    // weights: 64 n' rows x 1KB, XOR-swizzled
  __shared__ unsigned char Ast[64 * 1024];   // A panel: 64 b rows x 1KB, XOR-swizzled
  __shared__ float gates[64 * 68];           // [n'rel][brel] exchange, stride 68

  const int tid = threadIdx.x;
  const int lane = tid & 63;
  const int w = tid >> 6;
  const int wb = w >> 1, wn = w & 1;
  const int bid = blockIdx.x;
  const int layer = (bid & 7) >> 1;
  const int wgl = ((bid >> 3) << 1) | (bid & 1);
  const int b0g = wgl >> 4;
  const int b0 = b0g * 64;
  const int ntile = wgl & 15;
  const int n0 = ntile * 64;
  const int j0 = ntile * 16;
  const int mygrp = layer * 4 + b0g;

  // ---- load resident weight slice into LDS (once) ----
  const int ngr = (layer == 0) ? 36 : 64;
  for (int i = tid; i < 64 * ngr; i += 256) {
    int row = i / ngr, blk = i % ngr;
    uint4 v;
    if (layer == 0) {
      if (blk < 4) v = *(const uint4*)(wih0r + (size_t)(n0 + row) * 32 + blk * 8);
      else v = *(const uint4*)(whhr + (size_t)(n0 + row) * 256 + (blk - 4) * 8);
    } else {
      if (blk < 32)
        v = *(const uint4*)(wihr + ((size_t)(layer - 1) * 1024 + n0 + row) * 256 + blk * 8);
      else
        v = *(const uint4*)(whhr + ((size_t)layer * 1024 + n0 + row) * 256 + (blk - 32) * 8);
    }
    *(uint4*)(Ws + row * 1024 + ((blk * 16) ^ ((row & 15) << 4))) = v;
  }
  const float bv0 = biasr[layer * 1024 + n0 + wn * 32 + (lane & 15)];
  const float bv1 = biasr[layer * 1024 + n0 + wn * 32 + 16 + (lane & 15)];
  __syncthreads();

  const int arow0 = wb * 32 + (lane & 15);   // RELATIVE b row in Ast
  const int arow1 = arow0 + 16;
  const int akoff2 = (lane >> 4) * 16;       // byte offset within 32-K chunk
  const int brow0 = wn * 32 + (lane & 15);
  const int brow1 = brow0 + 16;

  const int stg_blk = tid & 63;              // staging granule column (constant)
  const int stg_r0 = tid >> 6;               // staging base row

  f32x4 creg = {0.f, 0.f, 0.f, 0.f};

  for (int t = 0; t < T; ++t) {
    // ---- dataflow wait: single thread polls 3 counters ----
    if (tid == 0) {
      const unsigned* frec = (t > 0) ? &flags[mygrp * 512 + (t - 1)] : nullptr;
      const unsigned* fprev = (layer > 0) ? &flags[(mygrp - 4) * 512 + t] : nullptr;
      const unsigned* fdown = (layer < 3 && t >= 4) ? &flags[(mygrp + 4) * 512 + (t - 4)] : nullptr;
      for (;;) {
        unsigned a = frec ? ldflag(frec) : 16u;
        unsigned b = fprev ? ldflag(fprev) : 16u;
        unsigned c = fdown ? ldflag(fdown) : 16u;
        if (a >= 16u && b >= 16u && c >= 16u) break;
        __builtin_amdgcn_s_sleep(1);
      }
    }
    __syncthreads();
    asm volatile("" ::: "memory");

    // ---- cooperative A-panel staging into LDS (batched coherent loads) ----
    const unsigned short* hbR = hbuf + ((size_t)layer * 4 + ((t + 3) & 3)) * 65536;
    if (layer == 0) {
      u64 qa[16], qb[16];
#pragma unroll
      for (int it = 0; it < 16; ++it) {
        int row = b0 + stg_r0 + it * 4;
        if (stg_blk < 4) {
          bf16x8 v = ldb8(xbf + ((size_t)row * T + t) * 32 + stg_blk * 8);
          qa[it] = ((const u64*)&v)[0];
          qb[it] = ((const u64*)&v)[1];
        } else if (stg_blk < 36) {
          const u64* s = (const u64*)(hbR + (size_t)row * 256 + (stg_blk - 4) * 8);
          qa[it] = ldq(s);
          qb[it] = ldq(s + 1);
        }
      }
      __builtin_amdgcn_sched_barrier(0);
      if (stg_blk < 36) {
#pragma unroll
        for (int it = 0; it < 16; ++it) {
          int row = stg_r0 + it * 4;
          uint4 v;
          ((u64*)&v)[0] = qa[it];
          ((u64*)&v)[1] = qb[it];
          *(uint4*)(Ast + row * 1024 + ((stg_blk * 16) ^ ((row & 15) << 4))) = v;
        }
      }
    } else {
      const unsigned short* hbP = hbuf + ((size_t)(layer - 1) * 4 + (t & 3)) * 65536;
      const unsigned short* src = (stg_blk < 32) ? hbP + stg_blk * 8 : hbR + (stg_blk - 32) * 8;
      u64 qa[16], qb[16];
#pragma unroll
      for (int it = 0; it < 16; ++it) {
        int row = b0 + stg_r0 + it * 4;
        const u64* s = (const u64*)(src + (size_t)row * 256);
        qa[it] = ldq(s);
        qb[it] = ldq(s + 1);
      }
      __builtin_amdgcn_sched_barrier(0);
#pragma unroll
      for (int it = 0; it < 16; ++it) {
        int row = stg_r0 + it * 4;
        uint4 v;
        ((u64*)&v)[0] = qa[it];
        ((u64*)&v)[1] = qb[it];
        *(uint4*)(Ast + row * 1024 + ((stg_blk * 16) ^ ((row & 15) << 4))) = v;
      }
    }
    __syncthreads();

    // ---- MFMA over K chunks (A and B both from swizzled LDS) ----
    f32x4 a00 = {bv0, bv0, bv0, bv0};
    f32x4 a01 = {bv1, bv1, bv1, bv1};
    f32x4 a10 = a00, a11 = a01;
    if (layer == 0) {
#pragma unroll
      for (int ki = 0; ki < 9; ++ki)
        mstep(Ast, Ws, ki * 64 + akoff2, arow0, arow1, brow0, brow1, a00, a01, a10, a11);
    } else {
#pragma unroll
      for (int ki = 0; ki < 16; ++ki)
        mstep(Ast, Ws, ki * 64 + akoff2, arow0, arow1, brow0, brow1, a00, a01, a10, a11);
    }

    // scatter acc frags to LDS: gates[n'rel][brel]
    {
      int c = lane & 15, Rg = lane >> 4;
      *(f32x4*)&gates[(wn * 32 + c) * 68 + wb * 32 + Rg * 4] = a00;
      *(f32x4*)&gates[(wn * 32 + 16 + c) * 68 + wb * 32 + Rg * 4] = a01;
      *(f32x4*)&gates[(wn * 32 + c) * 68 + wb * 32 + 16 + Rg * 4] = a10;
      *(f32x4*)&gates[(wn * 32 + 16 + c) * 68 + wb * 32 + 16 + Rg * 4] = a11;
    }
    __syncthreads();

    // activations + cell update (c in regs) + coherent h store
    {
      int brel = tid & 63, jq = tid >> 6;
      int b = b0 + brel;
      int jb = j0 + jq * 4;
      f32x4 cnew;
      float hv[4];
#pragma unroll
      for (int i2 = 0; i2 < 4; ++i2) {
        int jr = jq * 4 + i2;
        float ip = gates[(4 * jr + 0) * 68 + brel];
        float fp = gates[(4 * jr + 1) * 68 + brel];
        float gp = gates[(4 * jr + 2) * 68 + brel];
        float op = gates[(4 * jr + 3) * 68 + brel];
        float ii = sigf(ip), ff = sigf(fp), gg = tanhfast(gp), oo = sigf(op);
        float cc = ff * creg[i2] + ii * gg;
        cnew[i2] = cc;
        hv[i2] = oo * tanhfast(cc);
      }
      creg = cnew;
      u16x4 h4 = {f2bf(hv[0]), f2bf(hv[1]), f2bf(hv[2]), f2bf(hv[3])};
      stg_coh8(hbuf + ((size_t)layer * 4 + (t & 3)) * 65536 + (size_t)b * H + jb,
               __builtin_bit_cast(u64, h4));
      if (layer == 3 && t == T - 1) {
        float2 p01 = make_float2(hv[0], hv[1]);
        float2 p23 = make_float2(hv[2], hv[3]);
        stg_coh8(h3f + (size_t)b * H + jb, __builtin_bit_cast(u64, p01));
        stg_coh8(h3f + (size_t)b * H + jb + 2, __builtin_bit_cast(u64, p23));
      }
    }
    // drain write-through stores, then publish (fire-and-forget atomicAdd)
    asm volatile("s_waitcnt vmcnt(0)" ::: "memory");
    __syncthreads();
    if (tid == 0)
      __hip_atomic_fetch_add(&flags[mygrp * 512 + t], 1u, __ATOMIC_RELAXED,
                             __HIP_MEMORY_SCOPE_AGENT);
  }

  // ---- final projection by layer-3 WGs: 4 b each ----
  if (layer == 3) {
    if (tid == 0) {
      while (ldflag(&flags[mygrp * 512 + (T - 1)]) < 16u) __builtin_amdgcn_s_sleep(1);
    }
    __syncthreads();
    asm volatile("" ::: "memory");
    for (int i = tid; i < 4 * 128; i += 256) {
      int bi = i >> 7, jj = (i & 127) * 2;
      u64 q = ldq((const u64*)(h3f + (size_t)(b0 + ntile * 4 + bi) * H + jj));
      float2 hf = __builtin_bit_cast(float2, q);
      gates[bi * 260 + jj] = hf.x;
      gates[bi * 260 + jj + 1] = hf.y;
    }
    __syncthreads();
    if (tid < 4 * OUTD) {
      int o = tid % OUTD, bi = tid / OUTD;
      int b = b0 + ntile * 4 + bi;
      const float* wr = Wout + (size_t)o * H;
      const float* hr = &gates[bi * 260];
      float sum = bout[o];
#pragma unroll 8
      for (int j = 0; j < H; ++j) sum = fmaf(hr[j], wr[j], sum);
      out[b * OUTD + o] = sigf(sum);
    }
  }
}

extern "C" void kernel_launch(void* const* d_in, const int* in_sizes, int n_in,
                              void* d_out, int out_size, void* d_ws, size_t ws_size,
                              hipStream_t stream) {
  const float* x = (const float*)d_in[0];
  const float* Wih0 = (const float*)d_in[1];
  const float* WihRest = (const float*)d_in[2];
  const float* Whh = (const float*)d_in[3];
  const float* bih = (const float*)d_in[4];
  const float* bhh = (const float*)d_in[5];
  const float* Wout = (const float*)d_in[6];
  const float* bout = (const float*)d_in[7];
  float* out = (float*)d_out;
  char* ws = (char*)d_ws;

  unsigned* flags = (unsigned*)(ws + WS_FLAGS);
  unsigned short* hbuf = (unsigned short*)(ws + WS_HBUF);
  float* h3f = (float*)(ws + WS_H3F);
  unsigned short* xbf = (unsigned short*)(ws + WS_XBF);
  unsigned short* wih0r = (unsigned short*)(ws + WS_WIH0);
  unsigned short* wihr = (unsigned short*)(ws + WS_WIHR);
  unsigned short* whhr = (unsigned short*)(ws + WS_WHHR);
  float* biasr = (float*)(ws + WS_BIAS);

  hipMemsetAsync(ws, 0, (size_t)WS_ZERO, stream);
  prep_x<<<2048, 256, 0, stream>>>(x, xbf);
  prep_w<<<2048, 256, 0, stream>>>(Wih0, WihRest, Whh, bih, bhh, wih0r, wihr, whhr, biasr);
  lstm_main<<<NWG, 256, 0, stream>>>(xbf, wih0r, wihr, whhr, biasr, Wout, bout, hbuf,
                                     h3f, flags, out);
}